// Round 17
// baseline (286.411 us; speedup 1.0000x reference)
//
#include <hip/hip_runtime.h>

// VectorQuantizer: B=16, T=4096, D=256, K=1024 (fp32 in/out)
// N = B*T = 65536. out[n] = codebook[argmin_k ||x_n - c_k||^2]
//
// Two kernels:
//   P) prep: c2 (fp64) + codebook -> (-2*cb) bf16 hi/lo pre-swizzled tiles.
//   B) assign (R14-proven config: 16 pts/wave, VGPR~64, 4 blocks/CU):
//      16x16x32 MFMA, 3 chains (-2c)h.xh + (-2c)h.xl + (-2c)l.xh, chain0
//      seeded with c2 -> m = c2 - 2*x.c (err sigma ~1e-4). Per-point top-2;
//      gap < EPS_FLAG=8e-3 -> INLINE exact fp64 re-check in the block tail
//      (bit-equivalent to round-6 PASS: direct-difference, ordered top-2,
//      tie rule "runner-up within TIE_TOL=3.5e-5 and lower index wins").

#define DIMS   256
#define NCODE  1024
#define NPTS   65536
#define BMBLK  64           // points per block (4 waves x 16)
#define NT     64           // 16-code tiles
#define TB     16384        // bytes per tile (hi 8K + lo 8K)
#define EPS_FLAG 8.0e-3f
#define TIE_TOL  3.5e-5
#define FLTMAX   3.402823466e+38f
#define CBT_OFF  327680     // byte offset of bf16 codebook tiles in d_ws

typedef __attribute__((ext_vector_type(8))) short bf16x8;   // 4 VGPR
typedef __attribute__((ext_vector_type(4))) float f32x4;    // 4 VGPR

// float*s -> bf16 (RNE) hi + exact-residual lo
__device__ __forceinline__ void cvt8s(const float4& a, const float4& b, float s,
                                      bf16x8& h, bf16x8& l) {
    float f[8] = {a.x*s, a.y*s, a.z*s, a.w*s, b.x*s, b.y*s, b.z*s, b.w*s};
    #pragma unroll
    for (int e = 0; e < 8; ++e) {
        unsigned u  = __float_as_uint(f[e]);
        unsigned hr = u + 0x7FFFu + ((u >> 16) & 1u);
        unsigned short hs = (unsigned short)(hr >> 16);
        float hf = __uint_as_float((unsigned)hs << 16);
        float lo = f[e] - hf;                       // exact
        unsigned ul = __float_as_uint(lo);
        unsigned lr = ul + 0x7FFFu + ((ul >> 16) & 1u);
        h[e] = (short)hs;
        l[e] = (short)(lr >> 16);
    }
}

// ---------- kernel P: c2 (fp64) + codebook cvt to swizzled tiles ----------
// Tile t (16 codes): base = t*16384; hi [0,8192), lo [8192,16384).
// Within: off(r,p) = (r*512 + p*16) ^ ((r&7)<<4), r = code&15, p = 8-dim chunk.
__global__ __launch_bounds__(256) void vq_prep_kernel(const float* __restrict__ cb,
                                                      float* __restrict__ c2f,
                                                      char* __restrict__ cbt) {
    const int chunk = blockIdx.x * 256 + threadIdx.x;    // [0, 32768)
    const int k = chunk >> 5;                            // code
    const int p = chunk & 31;                            // 8-dim chunk
    const float4* src = (const float4*)(cb + (size_t)k * DIMS + p * 8);
    float4 a = src[0], b = src[1];

    double s = (double)a.x*a.x + (double)a.y*a.y + (double)a.z*a.z + (double)a.w*a.w
             + (double)b.x*b.x + (double)b.y*b.y + (double)b.z*b.z + (double)b.w*b.w;
    #pragma unroll
    for (int off = 16; off > 0; off >>= 1) s += __shfl_xor(s, off, 64);
    if (p == 0) c2f[k] = (float)s;

    bf16x8 h, l;
    cvt8s(a, b, -2.0f, h, l);
    const int t = k >> 4, r = k & 15;
    const int soff = (r * 512 + p * 16) ^ ((r & 7) << 4);
    *(bf16x8*)(cbt + (size_t)t * TB + soff)        = h;
    *(bf16x8*)(cbt + (size_t)t * TB + 8192 + soff) = l;
}

// DMA one wave-quarter (4KB) of tile t into LDS buffer
__device__ __forceinline__ void stage(const char* __restrict__ cbt, int t,
                                      char* dst, int w, int lane) {
    const char* src = cbt + (size_t)t * TB + w * 4096 + lane * 16;
    char* d = dst + w * 4096;
    #pragma unroll
    for (int i = 0; i < 4; ++i)
        __builtin_amdgcn_global_load_lds(
            (const __attribute__((address_space(1))) unsigned int*)(src + i * 1024),
            (__attribute__((address_space(3))) unsigned int*)(d + i * 1024),
            16, 0, 0);
}

// ---------- kernel B: 16x16x32 MFMA assign + inline exact recheck ----------
__global__ __launch_bounds__(256, 4) void vq_assign_kernel(const float* __restrict__ x,
                                                           const float* __restrict__ cb,
                                                           const char* __restrict__ cbt,
                                                           const float* __restrict__ c2f,
                                                           float* __restrict__ out) {
    __shared__ __attribute__((aligned(16))) char ldsbuf[2][TB];   // 32 KiB dbuf

    const int tid  = threadIdx.x;
    const int lane = tid & 63;
    const int w    = tid >> 6;
    const int n0   = blockIdx.x * BMBLK;

    // ---- stage tile 0 via global_load_lds ----
    stage(cbt, 0, ldsbuf[0], w, lane);

    // ---- x fragments: 16 points/wave, hi+lo, K=256 (8 chunks of 32) ----
    bf16x8 xh[8], xl[8];
    {
        const float* xrow = x + (size_t)(n0 + w * 16 + (lane & 15)) * DIMS;
        const int ks = (lane >> 4) * 8;
        #pragma unroll
        for (int kc = 0; kc < 8; ++kc) {
            float4 a = *(const float4*)(xrow + kc * 32 + ks);
            float4 b = *(const float4*)(xrow + kc * 32 + ks + 4);
            cvt8s(a, b, 1.0f, xh[kc], xl[kc]);
        }
    }
    __syncthreads();

    float tb1 = FLTMAX, tb2 = FLTMAX;
    int   ti1 = 0,      ti2 = 0;

    const int r  = lane & 15;            // A-frag row (code within tile)
    const int sl = lane >> 4;            // k-slice
    const int rowbase = r * 512 + sl * 16;
    const int sw = (r & 7) << 4;

    for (int t = 0; t < NT; ++t) {
        const int buf = t & 1;

        if (t + 1 < NT)                  // prefetch next tile (pure DMA)
            stage(cbt, t + 1, ldsbuf[buf ^ 1], w, lane);

        const char* bh = &ldsbuf[buf][0];
        const char* bl = &ldsbuf[buf][8192];

        // C/D: col = lane&15 (point), row = sl*4 + j (code)  [m89]
        const int cb0 = t * 16 + sl * 4;
        float4 cs = *(const float4*)&c2f[cb0];       // L1-broadcast global read
        f32x4 a0 = { cs.x, cs.y, cs.z, cs.w };
        f32x4 a1 = { 0.f, 0.f, 0.f, 0.f };
        f32x4 a2 = { 0.f, 0.f, 0.f, 0.f };

        #pragma unroll
        for (int kc = 0; kc < 8; ++kc) {
            const int byt = (rowbase + kc * 64) ^ sw;
            bf16x8 ch = *(const bf16x8*)(bh + byt);
            bf16x8 cl = *(const bf16x8*)(bl + byt);
            a0 = __builtin_amdgcn_mfma_f32_16x16x32_bf16(ch, xh[kc], a0, 0, 0, 0);
            a1 = __builtin_amdgcn_mfma_f32_16x16x32_bf16(ch, xl[kc], a1, 0, 0, 0);
            a2 = __builtin_amdgcn_mfma_f32_16x16x32_bf16(cl, xh[kc], a2, 0, 0, 0);
        }

        // ---- epilogue: m = c2 - 2*x.c (R11 order), running top-2 ----
        #pragma unroll
        for (int j = 0; j < 4; ++j) {
            const int code = cb0 + j;
            float m = (a0[j] + a1[j]) + a2[j];
            if (m < tb1)      { tb2 = tb1; ti2 = ti1; tb1 = m; ti1 = code; }
            else if (m < tb2) { tb2 = m; ti2 = code; }
        }

        __syncthreads();   // frees buf for next prefetch + drains DMA
    }

    // ---- merge across lanes {p, p+16, p+32, p+48} (disjoint code subsets) ----
    #pragma unroll
    for (int off = 16; off <= 32; off <<= 1) {
        float ob1 = __shfl_xor(tb1, off, 64);
        int   oi1 = __shfl_xor(ti1, off, 64);
        float ob2 = __shfl_xor(tb2, off, 64);
        int   oi2 = __shfl_xor(ti2, off, 64);
        float nb1, ca, cs2; int ni1, cai, csi;
        bool oless = (ob1 < tb1) || (ob1 == tb1 && oi1 < ti1);
        if (oless) { nb1 = ob1; ni1 = oi1; ca = tb1; cai = ti1; cs2 = ob2; csi = oi2; }
        else       { nb1 = tb1; ni1 = ti1; ca = ob1; cai = oi1; cs2 = tb2; csi = ti2; }
        if (cs2 < ca || (cs2 == ca && csi < cai)) { tb2 = cs2; ti2 = csi; }
        else                                      { tb2 = ca;  ti2 = cai; }
        tb1 = nb1; ti1 = ni1;
    }

    // ---- wave-local gather (provisional for flagged): out[p] = cb[best] ----
    #pragma unroll 4
    for (int p = 0; p < 16; ++p) {
        const int row = __shfl(ti1, p, 64);
        const float4* srcr = (const float4*)(cb + (size_t)row * DIMS);
        float4*       dstr = (float4*)(out + (size_t)(n0 + w * 16 + p) * DIMS);
        dstr[lane] = srcr[lane];                  // 64 lanes x 16B = 1 row
    }

    // ==== inline exact fp64 re-check (round-6 semantics), rare tail ====
    // LDS aliases ldsbuf (free after final main-loop barrier; gather uses no LDS)
    double* xsd   = (double*)&ldsbuf[0][0];       // 256 dbl
    double* lb1   = (double*)&ldsbuf[0][2048];    // 256 dbl
    double* lb2   = (double*)&ldsbuf[0][4096];    // 256 dbl
    int*    li1   = (int*)&ldsbuf[0][6144];       // 256 int
    int*    li2   = (int*)&ldsbuf[0][7168];       // 256 int
    int*    flagc = (int*)&ldsbuf[0][8192];
    int*    flagl = (int*)&ldsbuf[0][8256];       // up to 64 entries
    int*    selp  = (int*)&ldsbuf[0][8576];

    if (tid == 0) flagc[0] = 0;
    __syncthreads();
    if (lane < 16 && (tb2 - tb1 < EPS_FLAG)) {
        int pos = atomicAdd(flagc, 1);
        flagl[pos] = w * 16 + lane;               // point within block
    }
    __syncthreads();
    const int nflag = flagc[0];

    for (int f = 0; f < nflag; ++f) {
        const int n = n0 + flagl[f];
        xsd[tid] = (double)x[(size_t)n * DIMS + tid];
        __syncthreads();

        double b1 = 1.0e300, b2 = 1.0e300;
        int    j1 = 0,       j2 = 0;
        const int k0 = tid * 4;                   // ascending codes per thread
        #pragma unroll
        for (int j = 0; j < 4; ++j) {
            const int k = k0 + j;
            const float* cr = cb + (size_t)k * DIMS;
            double a0 = 0, a1 = 0, a2 = 0, a3 = 0;
            for (int d = 0; d < DIMS; d += 4) {
                double t0 = xsd[d]     - (double)cr[d];
                double t1 = xsd[d + 1] - (double)cr[d + 1];
                double t2 = xsd[d + 2] - (double)cr[d + 2];
                double t3 = xsd[d + 3] - (double)cr[d + 3];
                a0 = fma(t0, t0, a0);
                a1 = fma(t1, t1, a1);
                a2 = fma(t2, t2, a2);
                a3 = fma(t3, t3, a3);
            }
            double v = (a0 + a1) + (a2 + a3);
            if (v < b1)      { b2 = b1; j2 = j1; b1 = v; j1 = k; }
            else if (v < b2) { b2 = v; j2 = k; }
        }
        lb1[tid] = b1; li1[tid] = j1;
        lb2[tid] = b2; li2[tid] = j2;
        __syncthreads();

        if (tid == 0) {
            double B1 = 1.0e300, B2 = 1.0e300;
            int    J1 = 0,       J2 = 0;
            for (int e = 0; e < 256; ++e) {
                double v = lb1[e]; int ii = li1[e];
                if (v < B1 || (v == B1 && ii < J1)) { B2 = B1; J2 = J1; B1 = v; J1 = ii; }
                else if (v < B2 || (v == B2 && ii < J2)) { B2 = v; J2 = ii; }
                v = lb2[e]; ii = li2[e];
                if (v < B1 || (v == B1 && ii < J1)) { B2 = B1; J2 = J1; B1 = v; J1 = ii; }
                else if (v < B2 || (v == B2 && ii < J2)) { B2 = v; J2 = ii; }
            }
            selp[0] = (B2 - B1 < TIE_TOL && J2 < J1) ? J2 : J1;
        }
        __syncthreads();

        const float4* cb4 = (const float4*)(cb + (size_t)selp[0] * DIMS);
        float4*       o4  = (float4*)(out + (size_t)n * DIMS);
        if (tid < 64) o4[tid] = cb4[tid];
        __syncthreads();   // protect xsd/lb/sel before next flagged point
    }
}

extern "C" void kernel_launch(void* const* d_in, const int* in_sizes, int n_in,
                              void* d_out, int out_size, void* d_ws, size_t ws_size,
                              hipStream_t stream) {
    const float* x  = (const float*)d_in[0];   // [16,4096,256]
    const float* cb = (const float*)d_in[1];   // [1024,256]
    float* out = (float*)d_out;                // [16,4096,256]

    float* c2f = (float*)d_ws;                           // 1024 floats
    char*  cbt = (char*)d_ws + CBT_OFF;                  // 1 MiB bf16 tiles

    vq_prep_kernel<<<128, 256, 0, stream>>>(cb, c2f, cbt);
    vq_assign_kernel<<<NPTS / BMBLK, 256, 0, stream>>>(x, cb, cbt, c2f, out);
}

// Round 18
// 239.827 us; speedup vs baseline: 1.1942x; 1.1942x over previous
//
#include <hip/hip_runtime.h>

// VectorQuantizer: B=16, T=4096, D=256, K=1024 (fp32 in/out)
// N = B*T = 65536. out[n] = codebook[argmin_k ||x_n - c_k||^2]
//
// Two-tier (verified R6..R17 semantics):
//   1) bf16-split MFMA assign (R14-verbatim, 118us proven): 16x16x32,
//      3 chains (-2c)h.xh + (-2c)h.xl + (-2c)l.xh, chain0 seeded with c2
//      -> m = c2 - 2*x.c (err sigma ~1e-4). Per-point top-2;
//      gap < EPS_FLAG=8e-3 -> exact re-check.
//   2) fp64 refine, COALESCED per-code scan (R17 lesson: per-thread-row
//      scan was ~25us/point): wave w owns codes k==w mod 4 ascending;
//      lane l loads cb[k][4l..4l+3] float4; fp64 butterfly reduce;
//      top-2 + tie rule "runner-up within TIE_TOL=3.5e-5 and lower index
//      wins" (fp64 order-insensitive at 1e-13 << 3.5e-5).

#define DIMS   256
#define NCODE  1024
#define NPTS   65536
#define BMBLK  64           // points per block (4 waves x 16)
#define NT     64           // 16-code tiles
#define TB     16384        // bytes per tile (hi 8K + lo 8K)
#define EPS_FLAG 8.0e-3f
#define TIE_TOL  3.5e-5
#define FLTMAX   3.402823466e+38f
#define CBT_OFF  327680     // byte offset of bf16 codebook tiles in d_ws

typedef __attribute__((ext_vector_type(8))) short bf16x8;   // 4 VGPR
typedef __attribute__((ext_vector_type(4))) float f32x4;    // 4 VGPR

// float*s -> bf16 (RNE) hi + exact-residual lo
__device__ __forceinline__ void cvt8s(const float4& a, const float4& b, float s,
                                      bf16x8& h, bf16x8& l) {
    float f[8] = {a.x*s, a.y*s, a.z*s, a.w*s, b.x*s, b.y*s, b.z*s, b.w*s};
    #pragma unroll
    for (int e = 0; e < 8; ++e) {
        unsigned u  = __float_as_uint(f[e]);
        unsigned hr = u + 0x7FFFu + ((u >> 16) & 1u);
        unsigned short hs = (unsigned short)(hr >> 16);
        float hf = __uint_as_float((unsigned)hs << 16);
        float lo = f[e] - hf;                       // exact
        unsigned ul = __float_as_uint(lo);
        unsigned lr = ul + 0x7FFFu + ((ul >> 16) & 1u);
        h[e] = (short)hs;
        l[e] = (short)(lr >> 16);
    }
}

// ---------- kernel P: cnt=0 + c2 (fp64) + codebook cvt to swizzled tiles ----
__global__ __launch_bounds__(256) void vq_prep_kernel(const float* __restrict__ cb,
                                                      float* __restrict__ c2f,
                                                      char* __restrict__ cbt,
                                                      int* __restrict__ cnt) {
    if (blockIdx.x == 0 && threadIdx.x == 0) cnt[0] = 0;
    const int chunk = blockIdx.x * 256 + threadIdx.x;    // [0, 32768)
    const int k = chunk >> 5;                            // code
    const int p = chunk & 31;                            // 8-dim chunk
    const float4* src = (const float4*)(cb + (size_t)k * DIMS + p * 8);
    float4 a = src[0], b = src[1];

    double s = (double)a.x*a.x + (double)a.y*a.y + (double)a.z*a.z + (double)a.w*a.w
             + (double)b.x*b.x + (double)b.y*b.y + (double)b.z*b.z + (double)b.w*b.w;
    #pragma unroll
    for (int off = 16; off > 0; off >>= 1) s += __shfl_xor(s, off, 64);
    if (p == 0) c2f[k] = (float)s;

    bf16x8 h, l;
    cvt8s(a, b, -2.0f, h, l);
    const int t = k >> 4, r = k & 15;
    const int soff = (r * 512 + p * 16) ^ ((r & 7) << 4);
    *(bf16x8*)(cbt + (size_t)t * TB + soff)        = h;
    *(bf16x8*)(cbt + (size_t)t * TB + 8192 + soff) = l;
}

// DMA one wave-quarter (4KB) of tile t into LDS buffer
__device__ __forceinline__ void stage(const char* __restrict__ cbt, int t,
                                      char* dst, int w, int lane) {
    const char* src = cbt + (size_t)t * TB + w * 4096 + lane * 16;
    char* d = dst + w * 4096;
    #pragma unroll
    for (int i = 0; i < 4; ++i)
        __builtin_amdgcn_global_load_lds(
            (const __attribute__((address_space(1))) unsigned int*)(src + i * 1024),
            (__attribute__((address_space(3))) unsigned int*)(d + i * 1024),
            16, 0, 0);
}

// ---------- kernel B: 16x16x32 MFMA assign (R14-verbatim) ----------
__global__ __launch_bounds__(256, 4) void vq_assign_kernel(const float* __restrict__ x,
                                                           const float* __restrict__ cb,
                                                           const char* __restrict__ cbt,
                                                           const float* __restrict__ c2f,
                                                           float* __restrict__ out,
                                                           int* __restrict__ cnt,
                                                           int* __restrict__ list) {
    __shared__ __attribute__((aligned(16))) char ldsbuf[2][TB];   // 32 KiB dbuf

    const int tid  = threadIdx.x;
    const int lane = tid & 63;
    const int w    = tid >> 6;
    const int n0   = blockIdx.x * BMBLK;

    stage(cbt, 0, ldsbuf[0], w, lane);

    bf16x8 xh[8], xl[8];
    {
        const float* xrow = x + (size_t)(n0 + w * 16 + (lane & 15)) * DIMS;
        const int ks = (lane >> 4) * 8;
        #pragma unroll
        for (int kc = 0; kc < 8; ++kc) {
            float4 a = *(const float4*)(xrow + kc * 32 + ks);
            float4 b = *(const float4*)(xrow + kc * 32 + ks + 4);
            cvt8s(a, b, 1.0f, xh[kc], xl[kc]);
        }
    }
    __syncthreads();

    float tb1 = FLTMAX, tb2 = FLTMAX;
    int   ti1 = 0,      ti2 = 0;

    const int r  = lane & 15;
    const int sl = lane >> 4;
    const int rowbase = r * 512 + sl * 16;
    const int sw = (r & 7) << 4;

    for (int t = 0; t < NT; ++t) {
        const int buf = t & 1;

        if (t + 1 < NT)
            stage(cbt, t + 1, ldsbuf[buf ^ 1], w, lane);

        const char* bh = &ldsbuf[buf][0];
        const char* bl = &ldsbuf[buf][8192];

        const int cb0 = t * 16 + sl * 4;
        float4 cs = *(const float4*)&c2f[cb0];
        f32x4 a0 = { cs.x, cs.y, cs.z, cs.w };
        f32x4 a1 = { 0.f, 0.f, 0.f, 0.f };
        f32x4 a2 = { 0.f, 0.f, 0.f, 0.f };

        #pragma unroll
        for (int kc = 0; kc < 8; ++kc) {
            const int byt = (rowbase + kc * 64) ^ sw;
            bf16x8 ch = *(const bf16x8*)(bh + byt);
            bf16x8 cl = *(const bf16x8*)(bl + byt);
            a0 = __builtin_amdgcn_mfma_f32_16x16x32_bf16(ch, xh[kc], a0, 0, 0, 0);
            a1 = __builtin_amdgcn_mfma_f32_16x16x32_bf16(ch, xl[kc], a1, 0, 0, 0);
            a2 = __builtin_amdgcn_mfma_f32_16x16x32_bf16(cl, xh[kc], a2, 0, 0, 0);
        }

        #pragma unroll
        for (int j = 0; j < 4; ++j) {
            const int code = cb0 + j;
            float m = (a0[j] + a1[j]) + a2[j];
            if (m < tb1)      { tb2 = tb1; ti2 = ti1; tb1 = m; ti1 = code; }
            else if (m < tb2) { tb2 = m; ti2 = code; }
        }

        __syncthreads();
    }

    #pragma unroll
    for (int off = 16; off <= 32; off <<= 1) {
        float ob1 = __shfl_xor(tb1, off, 64);
        int   oi1 = __shfl_xor(ti1, off, 64);
        float ob2 = __shfl_xor(tb2, off, 64);
        int   oi2 = __shfl_xor(ti2, off, 64);
        float nb1, ca, cs2; int ni1, cai, csi;
        bool oless = (ob1 < tb1) || (ob1 == tb1 && oi1 < ti1);
        if (oless) { nb1 = ob1; ni1 = oi1; ca = tb1; cai = ti1; cs2 = ob2; csi = oi2; }
        else       { nb1 = tb1; ni1 = ti1; ca = ob1; cai = oi1; cs2 = tb2; csi = ti2; }
        if (cs2 < ca || (cs2 == ca && csi < cai)) { tb2 = cs2; ti2 = csi; }
        else                                      { tb2 = ca;  ti2 = cai; }
        tb1 = nb1; ti1 = ni1;
    }

    if (lane < 16) {
        const int lp = w * 16 + lane;
        if (tb2 - tb1 < EPS_FLAG) {
            int pos = atomicAdd(cnt, 1);
            list[pos] = n0 + lp;
        }
    }

    #pragma unroll 4
    for (int p = 0; p < 16; ++p) {
        const int row = __shfl(ti1, p, 64);
        const float4* srcr = (const float4*)(cb + (size_t)row * DIMS);
        float4*       dstr = (float4*)(out + (size_t)(n0 + w * 16 + p) * DIMS);
        dstr[lane] = srcr[lane];
    }
}

// ---------- kernel C: exact fp64 re-check, coalesced per-code scan ----------
__global__ __launch_bounds__(256) void vq_refine_kernel(const float* __restrict__ x,
                                                        const float* __restrict__ cb,
                                                        const int* __restrict__ cnt,
                                                        const int* __restrict__ list,
                                                        float* __restrict__ out) {
    __shared__ double wd1[4], wd2[4];
    __shared__ int    wi1[4], wi2[4];
    __shared__ int    sel;

    const int tid  = threadIdx.x;
    const int lane = tid & 63;
    const int w    = tid >> 6;
    const int count = cnt[0];

    for (int li = blockIdx.x; li < count; li += gridDim.x) {
        const int n = list[li];

        // lane l holds dims 4l..4l+3 of x (fp64)
        float4 xv = ((const float4*)(x + (size_t)n * DIMS))[lane];
        const double x0 = (double)xv.x, x1 = (double)xv.y;
        const double x2 = (double)xv.z, x3 = (double)xv.w;

        double b1 = 1.0e300, b2 = 1.0e300;
        int    i1 = 0,       i2 = 0;

        // wave w scans codes w, w+4, ... (ascending within wave)
        for (int k = w; k < NCODE; k += 4) {
            float4 cv = ((const float4*)(cb + (size_t)k * DIMS))[lane];  // coalesced
            double t0 = x0 - (double)cv.x;
            double t1 = x1 - (double)cv.y;
            double t2 = x2 - (double)cv.z;
            double t3 = x3 - (double)cv.w;
            double s = fma(t0, t0, fma(t1, t1, fma(t2, t2, t3 * t3)));
            #pragma unroll
            for (int off = 32; off > 0; off >>= 1)
                s += __shfl_xor(s, off, 64);     // all lanes get full sum
            if (s < b1)      { b2 = b1; i2 = i1; b1 = s; i1 = k; }
            else if (s < b2) { b2 = s; i2 = k; }
        }

        if (lane == 0) { wd1[w] = b1; wi1[w] = i1; wd2[w] = b2; wi2[w] = i2; }
        __syncthreads();

        if (tid == 0) {
            double B1 = 1.0e300, B2 = 1.0e300;
            int    J1 = 0,       J2 = 0;
            #pragma unroll
            for (int g = 0; g < 4; ++g) {
                double v = wd1[g]; int ii = wi1[g];
                if (v < B1 || (v == B1 && ii < J1)) { B2 = B1; J2 = J1; B1 = v; J1 = ii; }
                else if (v < B2 || (v == B2 && ii < J2)) { B2 = v; J2 = ii; }
                v = wd2[g]; ii = wi2[g];
                if (v < B1 || (v == B1 && ii < J1)) { B2 = B1; J2 = J1; B1 = v; J1 = ii; }
                else if (v < B2 || (v == B2 && ii < J2)) { B2 = v; J2 = ii; }
            }
            sel = (B2 - B1 < TIE_TOL && J2 < J1) ? J2 : J1;
        }
        __syncthreads();

        const float4* cb4 = (const float4*)(cb + (size_t)sel * DIMS);
        float4*       o4  = (float4*)(out + (size_t)n * DIMS);
        if (tid < 64) o4[tid] = cb4[tid];
        __syncthreads();   // protect wd/sel before next list entry
    }
}

extern "C" void kernel_launch(void* const* d_in, const int* in_sizes, int n_in,
                              void* d_out, int out_size, void* d_ws, size_t ws_size,
                              hipStream_t stream) {
    const float* x  = (const float*)d_in[0];   // [16,4096,256]
    const float* cb = (const float*)d_in[1];   // [1024,256]
    float* out = (float*)d_out;                // [16,4096,256]

    float* c2f = (float*)d_ws;                           // 1024 floats
    int*   cnt = (int*)((char*)d_ws + 4096);             // 1 int
    int*   lst = (int*)((char*)d_ws + 4112);             // worklist
    char*  cbt = (char*)d_ws + CBT_OFF;                  // 1 MiB bf16 tiles

    vq_prep_kernel<<<128, 256, 0, stream>>>(cb, c2f, cbt, cnt);
    vq_assign_kernel<<<NPTS / BMBLK, 256, 0, stream>>>(x, cb, cbt, c2f, out, cnt, lst);
    vq_refine_kernel<<<256, 256, 0, stream>>>(x, cb, cnt, lst, out);
}

// Round 19
// 169.925 us; speedup vs baseline: 1.6855x; 1.4114x over previous
//
#include <hip/hip_runtime.h>

// VectorQuantizer: B=16, T=4096, D=256, K=1024 (fp32 in/out)
// N = B*T = 65536. out[n] = codebook[argmin_k ||x_n - c_k||^2]
//
// Two-tier (verified R6..R18 semantics):
//   1) bf16-split MFMA assign (R14-verbatim): 16x16x32, 3 chains
//      (-2c)h.xh + (-2c)h.xl + (-2c)l.xh, chain0 seeded with c2 ->
//      m = c2 - 2*x.c (err sigma ~1e-4). Per-point top-2;
//      gap < EPS_FLAG=8e-3 -> exact re-check (~4 points).
//   2) fp64 refine, ILP-unrolled coalesced scan (R18 lesson: serial
//      load->butterfly chain was 1275 cyc/code): wave w owns contiguous
//      codes [w*256,(w+1)*256), 8 codes/iter with independent FMA chains
//      + interleaved butterflies; top-2 + tie rule "runner-up within
//      TIE_TOL=3.5e-5 and lower index wins" (round-6 verified).

#define DIMS   256
#define NCODE  1024
#define NPTS   65536
#define BMBLK  64           // points per block (4 waves x 16)
#define NT     64           // 16-code tiles
#define TB     16384        // bytes per tile (hi 8K + lo 8K)
#define EPS_FLAG 8.0e-3f
#define TIE_TOL  3.5e-5
#define FLTMAX   3.402823466e+38f
#define CBT_OFF  327680     // byte offset of bf16 codebook tiles in d_ws

typedef __attribute__((ext_vector_type(8))) short bf16x8;   // 4 VGPR
typedef __attribute__((ext_vector_type(4))) float f32x4;    // 4 VGPR

// float*s -> bf16 (RNE) hi + exact-residual lo
__device__ __forceinline__ void cvt8s(const float4& a, const float4& b, float s,
                                      bf16x8& h, bf16x8& l) {
    float f[8] = {a.x*s, a.y*s, a.z*s, a.w*s, b.x*s, b.y*s, b.z*s, b.w*s};
    #pragma unroll
    for (int e = 0; e < 8; ++e) {
        unsigned u  = __float_as_uint(f[e]);
        unsigned hr = u + 0x7FFFu + ((u >> 16) & 1u);
        unsigned short hs = (unsigned short)(hr >> 16);
        float hf = __uint_as_float((unsigned)hs << 16);
        float lo = f[e] - hf;                       // exact
        unsigned ul = __float_as_uint(lo);
        unsigned lr = ul + 0x7FFFu + ((ul >> 16) & 1u);
        h[e] = (short)hs;
        l[e] = (short)(lr >> 16);
    }
}

// ---------- kernel P: cnt=0 + c2 (fp64) + codebook cvt to swizzled tiles ----
__global__ __launch_bounds__(256) void vq_prep_kernel(const float* __restrict__ cb,
                                                      float* __restrict__ c2f,
                                                      char* __restrict__ cbt,
                                                      int* __restrict__ cnt) {
    if (blockIdx.x == 0 && threadIdx.x == 0) cnt[0] = 0;
    const int chunk = blockIdx.x * 256 + threadIdx.x;    // [0, 32768)
    const int k = chunk >> 5;                            // code
    const int p = chunk & 31;                            // 8-dim chunk
    const float4* src = (const float4*)(cb + (size_t)k * DIMS + p * 8);
    float4 a = src[0], b = src[1];

    double s = (double)a.x*a.x + (double)a.y*a.y + (double)a.z*a.z + (double)a.w*a.w
             + (double)b.x*b.x + (double)b.y*b.y + (double)b.z*b.z + (double)b.w*b.w;
    #pragma unroll
    for (int off = 16; off > 0; off >>= 1) s += __shfl_xor(s, off, 64);
    if (p == 0) c2f[k] = (float)s;

    bf16x8 h, l;
    cvt8s(a, b, -2.0f, h, l);
    const int t = k >> 4, r = k & 15;
    const int soff = (r * 512 + p * 16) ^ ((r & 7) << 4);
    *(bf16x8*)(cbt + (size_t)t * TB + soff)        = h;
    *(bf16x8*)(cbt + (size_t)t * TB + 8192 + soff) = l;
}

// DMA one wave-quarter (4KB) of tile t into LDS buffer
__device__ __forceinline__ void stage(const char* __restrict__ cbt, int t,
                                      char* dst, int w, int lane) {
    const char* src = cbt + (size_t)t * TB + w * 4096 + lane * 16;
    char* d = dst + w * 4096;
    #pragma unroll
    for (int i = 0; i < 2; ++i)
        __builtin_amdgcn_global_load_lds(
            (const __attribute__((address_space(1))) unsigned int*)(src + i * 2048 + lane * 16 - lane * 16 + i * 0), // placeholder
            (__attribute__((address_space(3))) unsigned int*)(d + i * 2048),
            16, 0, 0);
}

// correct stage (4x 1KB slabs)
__device__ __forceinline__ void stage4(const char* __restrict__ cbt, int t,
                                       char* dst, int w, int lane) {
    const char* src = cbt + (size_t)t * TB + w * 4096 + lane * 16;
    char* d = dst + w * 4096;
    #pragma unroll
    for (int i = 0; i < 4; ++i)
        __builtin_amdgcn_global_load_lds(
            (const __attribute__((address_space(1))) unsigned int*)(src + i * 1024),
            (__attribute__((address_space(3))) unsigned int*)(d + i * 1024),
            16, 0, 0);
}

// ---------- kernel B: 16x16x32 MFMA assign (R14-verbatim) ----------
__global__ __launch_bounds__(256, 4) void vq_assign_kernel(const float* __restrict__ x,
                                                           const float* __restrict__ cb,
                                                           const char* __restrict__ cbt,
                                                           const float* __restrict__ c2f,
                                                           float* __restrict__ out,
                                                           int* __restrict__ cnt,
                                                           int* __restrict__ list) {
    __shared__ __attribute__((aligned(16))) char ldsbuf[2][TB];   // 32 KiB dbuf

    const int tid  = threadIdx.x;
    const int lane = tid & 63;
    const int w    = tid >> 6;
    const int n0   = blockIdx.x * BMBLK;

    stage4(cbt, 0, ldsbuf[0], w, lane);

    bf16x8 xh[8], xl[8];
    {
        const float* xrow = x + (size_t)(n0 + w * 16 + (lane & 15)) * DIMS;
        const int ks = (lane >> 4) * 8;
        #pragma unroll
        for (int kc = 0; kc < 8; ++kc) {
            float4 a = *(const float4*)(xrow + kc * 32 + ks);
            float4 b = *(const float4*)(xrow + kc * 32 + ks + 4);
            cvt8s(a, b, 1.0f, xh[kc], xl[kc]);
        }
    }
    __syncthreads();

    float tb1 = FLTMAX, tb2 = FLTMAX;
    int   ti1 = 0,      ti2 = 0;

    const int r  = lane & 15;
    const int sl = lane >> 4;
    const int rowbase = r * 512 + sl * 16;
    const int sw = (r & 7) << 4;

    for (int t = 0; t < NT; ++t) {
        const int buf = t & 1;

        if (t + 1 < NT)
            stage4(cbt, t + 1, ldsbuf[buf ^ 1], w, lane);

        const char* bh = &ldsbuf[buf][0];
        const char* bl = &ldsbuf[buf][8192];

        const int cb0 = t * 16 + sl * 4;
        float4 cs = *(const float4*)&c2f[cb0];
        f32x4 a0 = { cs.x, cs.y, cs.z, cs.w };
        f32x4 a1 = { 0.f, 0.f, 0.f, 0.f };
        f32x4 a2 = { 0.f, 0.f, 0.f, 0.f };

        #pragma unroll
        for (int kc = 0; kc < 8; ++kc) {
            const int byt = (rowbase + kc * 64) ^ sw;
            bf16x8 ch = *(const bf16x8*)(bh + byt);
            bf16x8 cl = *(const bf16x8*)(bl + byt);
            a0 = __builtin_amdgcn_mfma_f32_16x16x32_bf16(ch, xh[kc], a0, 0, 0, 0);
            a1 = __builtin_amdgcn_mfma_f32_16x16x32_bf16(ch, xl[kc], a1, 0, 0, 0);
            a2 = __builtin_amdgcn_mfma_f32_16x16x32_bf16(cl, xh[kc], a2, 0, 0, 0);
        }

        #pragma unroll
        for (int j = 0; j < 4; ++j) {
            const int code = cb0 + j;
            float m = (a0[j] + a1[j]) + a2[j];
            if (m < tb1)      { tb2 = tb1; ti2 = ti1; tb1 = m; ti1 = code; }
            else if (m < tb2) { tb2 = m; ti2 = code; }
        }

        __syncthreads();
    }

    #pragma unroll
    for (int off = 16; off <= 32; off <<= 1) {
        float ob1 = __shfl_xor(tb1, off, 64);
        int   oi1 = __shfl_xor(ti1, off, 64);
        float ob2 = __shfl_xor(tb2, off, 64);
        int   oi2 = __shfl_xor(ti2, off, 64);
        float nb1, ca, cs2; int ni1, cai, csi;
        bool oless = (ob1 < tb1) || (ob1 == tb1 && oi1 < ti1);
        if (oless) { nb1 = ob1; ni1 = oi1; ca = tb1; cai = ti1; cs2 = ob2; csi = oi2; }
        else       { nb1 = tb1; ni1 = ti1; ca = ob1; cai = oi1; cs2 = tb2; csi = ti2; }
        if (cs2 < ca || (cs2 == ca && csi < cai)) { tb2 = cs2; ti2 = csi; }
        else                                      { tb2 = ca;  ti2 = cai; }
        tb1 = nb1; ti1 = ni1;
    }

    if (lane < 16) {
        const int lp = w * 16 + lane;
        if (tb2 - tb1 < EPS_FLAG) {
            int pos = atomicAdd(cnt, 1);
            list[pos] = n0 + lp;
        }
    }

    #pragma unroll 4
    for (int p = 0; p < 16; ++p) {
        const int row = __shfl(ti1, p, 64);
        const float4* srcr = (const float4*)(cb + (size_t)row * DIMS);
        float4*       dstr = (float4*)(out + (size_t)(n0 + w * 16 + p) * DIMS);
        dstr[lane] = srcr[lane];
    }
}

// ---------- kernel C: exact fp64 re-check, ILP-unrolled coalesced scan ------
__global__ __launch_bounds__(256) void vq_refine_kernel(const float* __restrict__ x,
                                                        const float* __restrict__ cb,
                                                        const int* __restrict__ cnt,
                                                        const int* __restrict__ list,
                                                        float* __restrict__ out) {
    __shared__ double wd1[4], wd2[4];
    __shared__ int    wi1[4], wi2[4];
    __shared__ int    sel;

    const int tid  = threadIdx.x;
    const int lane = tid & 63;
    const int w    = tid >> 6;
    const int count = cnt[0];

    for (int li = blockIdx.x; li < count; li += gridDim.x) {
        const int n = list[li];

        // lane l holds dims 4l..4l+3 of x (fp64)
        float4 xv = ((const float4*)(x + (size_t)n * DIMS))[lane];
        const double x0 = (double)xv.x, x1 = (double)xv.y;
        const double x2 = (double)xv.z, x3 = (double)xv.w;

        double b1 = 1.0e300, b2 = 1.0e300;
        int    i1 = 0,       i2 = 0;

        // wave w owns contiguous codes [w*256, (w+1)*256), 8 codes/iter
        const int kw = w * 256;
        for (int kb = 0; kb < 256; kb += 8) {
            double s[8];
            #pragma unroll
            for (int u = 0; u < 8; ++u) {        // 8 independent load+FMA chains
                float4 cv = ((const float4*)(cb + (size_t)(kw + kb + u) * DIMS))[lane];
                double t0 = x0 - (double)cv.x;
                double t1 = x1 - (double)cv.y;
                double t2 = x2 - (double)cv.z;
                double t3 = x3 - (double)cv.w;
                s[u] = fma(t0, t0, fma(t1, t1, fma(t2, t2, t3 * t3)));
            }
            #pragma unroll
            for (int off = 32; off > 0; off >>= 1) {   // interleaved butterflies
                #pragma unroll
                for (int u = 0; u < 8; ++u)
                    s[u] += __shfl_xor(s[u], off, 64);
            }
            #pragma unroll
            for (int u = 0; u < 8; ++u) {        // ascending k: first-index wins
                const int k = kw + kb + u;
                if (s[u] < b1)      { b2 = b1; i2 = i1; b1 = s[u]; i1 = k; }
                else if (s[u] < b2) { b2 = s[u]; i2 = k; }
            }
        }

        if (lane == 0) { wd1[w] = b1; wi1[w] = i1; wd2[w] = b2; wi2[w] = i2; }
        __syncthreads();

        if (tid == 0) {
            double B1 = 1.0e300, B2 = 1.0e300;
            int    J1 = 0,       J2 = 0;
            #pragma unroll
            for (int g = 0; g < 4; ++g) {
                double v = wd1[g]; int ii = wi1[g];
                if (v < B1 || (v == B1 && ii < J1)) { B2 = B1; J2 = J1; B1 = v; J1 = ii; }
                else if (v < B2 || (v == B2 && ii < J2)) { B2 = v; J2 = ii; }
                v = wd2[g]; ii = wi2[g];
                if (v < B1 || (v == B1 && ii < J1)) { B2 = B1; J2 = J1; B1 = v; J1 = ii; }
                else if (v < B2 || (v == B2 && ii < J2)) { B2 = v; J2 = ii; }
            }
            sel = (B2 - B1 < TIE_TOL && J2 < J1) ? J2 : J1;
        }
        __syncthreads();

        const float4* cb4 = (const float4*)(cb + (size_t)sel * DIMS);
        float4*       o4  = (float4*)(out + (size_t)n * DIMS);
        if (tid < 64) o4[tid] = cb4[tid];
        __syncthreads();   // protect wd/sel before next list entry
    }
}

extern "C" void kernel_launch(void* const* d_in, const int* in_sizes, int n_in,
                              void* d_out, int out_size, void* d_ws, size_t ws_size,
                              hipStream_t stream) {
    const float* x  = (const float*)d_in[0];   // [16,4096,256]
    const float* cb = (const float*)d_in[1];   // [1024,256]
    float* out = (float*)d_out;                // [16,4096,256]

    float* c2f = (float*)d_ws;                           // 1024 floats
    int*   cnt = (int*)((char*)d_ws + 4096);             // 1 int
    int*   lst = (int*)((char*)d_ws + 4112);             // worklist
    char*  cbt = (char*)d_ws + CBT_OFF;                  // 1 MiB bf16 tiles

    vq_prep_kernel<<<128, 256, 0, stream>>>(cb, c2f, cbt, cnt);
    vq_assign_kernel<<<NPTS / BMBLK, 256, 0, stream>>>(x, cb, cbt, c2f, out, cnt, lst);
    vq_refine_kernel<<<256, 256, 0, stream>>>(x, cb, cnt, lst, out);
}

// Round 20
// 165.857 us; speedup vs baseline: 1.7269x; 1.0245x over previous
//
#include <hip/hip_runtime.h>

// VectorQuantizer: B=16, T=4096, D=256, K=1024 (fp32 in/out)
// N = B*T = 65536. out[n] = codebook[argmin_k ||x_n - c_k||^2]
//
// Two-tier (verified R6..R19 semantics):
//   1) bf16-split MFMA assign (R14 structure): 16x16x32, 3 chains
//      (-2c)h.xh + (-2c)h.xl + (-2c)l.xh, chain0 seeded with c2 ->
//      m = c2 - 2*x.c (err sigma ~1e-4). Per-point top-2;
//      gap < EPS_FLAG=8e-3 -> exact re-check (~4 points).
//      R20 change: codebook tile layout re-permuted to
//      off(kc,sl,r) = kc*1024 + sl*256 + r*16 so each ds_read_b128 by a
//      wave is 1KB CONTIGUOUS (R19 analysis: old XOR layout had lanes
//      r/r+8 colliding on bank-quads -> 65k conflict cyc/CU = 25% of the
//      binding LDS pipe).
//   2) fp64 refine, ILP-unrolled coalesced scan (R19-proven): 8 codes/iter
//      independent chains; top-2 + tie rule "runner-up within
//      TIE_TOL=3.5e-5 and lower index wins" (round-6 verified).

#define DIMS   256
#define NCODE  1024
#define NPTS   65536
#define BMBLK  64           // points per block (4 waves x 16)
#define NT     64           // 16-code tiles
#define TB     16384        // bytes per tile (hi 8K + lo 8K)
#define EPS_FLAG 8.0e-3f
#define TIE_TOL  3.5e-5
#define FLTMAX   3.402823466e+38f
#define CBT_OFF  327680     // byte offset of bf16 codebook tiles in d_ws

typedef __attribute__((ext_vector_type(8))) short bf16x8;   // 4 VGPR
typedef __attribute__((ext_vector_type(4))) float f32x4;    // 4 VGPR

// float*s -> bf16 (RNE) hi + exact-residual lo
__device__ __forceinline__ void cvt8s(const float4& a, const float4& b, float s,
                                      bf16x8& h, bf16x8& l) {
    float f[8] = {a.x*s, a.y*s, a.z*s, a.w*s, b.x*s, b.y*s, b.z*s, b.w*s};
    #pragma unroll
    for (int e = 0; e < 8; ++e) {
        unsigned u  = __float_as_uint(f[e]);
        unsigned hr = u + 0x7FFFu + ((u >> 16) & 1u);
        unsigned short hs = (unsigned short)(hr >> 16);
        float hf = __uint_as_float((unsigned)hs << 16);
        float lo = f[e] - hf;                       // exact
        unsigned ul = __float_as_uint(lo);
        unsigned lr = ul + 0x7FFFu + ((ul >> 16) & 1u);
        h[e] = (short)hs;
        l[e] = (short)(lr >> 16);
    }
}

// ---------- kernel P: cnt=0 + c2 (fp64) + codebook cvt to permuted tiles ----
// Tile t (16 codes): base = t*16384; hi [0,8192), lo [8192,16384).
// chunk p (dims 8p..8p+7) of code r (k&15): off = p*256 + r*16
//   (p = kc*4 + sl  ->  off = kc*1024 + sl*256 + r*16; wave-contiguous reads)
__global__ __launch_bounds__(256) void vq_prep_kernel(const float* __restrict__ cb,
                                                      float* __restrict__ c2f,
                                                      char* __restrict__ cbt,
                                                      int* __restrict__ cnt) {
    if (blockIdx.x == 0 && threadIdx.x == 0) cnt[0] = 0;
    const int chunk = blockIdx.x * 256 + threadIdx.x;    // [0, 32768)
    const int k = chunk >> 5;                            // code
    const int p = chunk & 31;                            // 8-dim chunk
    const float4* src = (const float4*)(cb + (size_t)k * DIMS + p * 8);
    float4 a = src[0], b = src[1];

    double s = (double)a.x*a.x + (double)a.y*a.y + (double)a.z*a.z + (double)a.w*a.w
             + (double)b.x*b.x + (double)b.y*b.y + (double)b.z*b.z + (double)b.w*b.w;
    #pragma unroll
    for (int off = 16; off > 0; off >>= 1) s += __shfl_xor(s, off, 64);
    if (p == 0) c2f[k] = (float)s;

    bf16x8 h, l;
    cvt8s(a, b, -2.0f, h, l);
    const int t = k >> 4, r = k & 15;
    const int soff = (p << 8) + (r << 4);                // p*256 + r*16
    *(bf16x8*)(cbt + (size_t)t * TB + soff)        = h;
    *(bf16x8*)(cbt + (size_t)t * TB + 8192 + soff) = l;
}

// DMA one wave-quarter (4KB) of tile t into LDS buffer
__device__ __forceinline__ void stage4(const char* __restrict__ cbt, int t,
                                       char* dst, int w, int lane) {
    const char* src = cbt + (size_t)t * TB + w * 4096 + lane * 16;
    char* d = dst + w * 4096;
    #pragma unroll
    for (int i = 0; i < 4; ++i)
        __builtin_amdgcn_global_load_lds(
            (const __attribute__((address_space(1))) unsigned int*)(src + i * 1024),
            (__attribute__((address_space(3))) unsigned int*)(d + i * 1024),
            16, 0, 0);
}

// ---------- kernel B: 16x16x32 MFMA assign (contiguous-read layout) --------
__global__ __launch_bounds__(256, 4) void vq_assign_kernel(const float* __restrict__ x,
                                                           const float* __restrict__ cb,
                                                           const char* __restrict__ cbt,
                                                           const float* __restrict__ c2f,
                                                           float* __restrict__ out,
                                                           int* __restrict__ cnt,
                                                           int* __restrict__ list) {
    __shared__ __attribute__((aligned(16))) char ldsbuf[2][TB];   // 32 KiB dbuf

    const int tid  = threadIdx.x;
    const int lane = tid & 63;
    const int w    = tid >> 6;
    const int n0   = blockIdx.x * BMBLK;

    stage4(cbt, 0, ldsbuf[0], w, lane);

    bf16x8 xh[8], xl[8];
    {
        const float* xrow = x + (size_t)(n0 + w * 16 + (lane & 15)) * DIMS;
        const int ks = (lane >> 4) * 8;
        #pragma unroll
        for (int kc = 0; kc < 8; ++kc) {
            float4 a = *(const float4*)(xrow + kc * 32 + ks);
            float4 b = *(const float4*)(xrow + kc * 32 + ks + 4);
            cvt8s(a, b, 1.0f, xh[kc], xl[kc]);
        }
    }
    __syncthreads();

    float tb1 = FLTMAX, tb2 = FLTMAX;
    int   ti1 = 0,      ti2 = 0;

    const int r  = lane & 15;            // A-frag row (code within tile)
    const int sl = lane >> 4;            // k-slice
    const int lanebase = sl * 256 + r * 16;   // contiguous across the wave

    for (int t = 0; t < NT; ++t) {
        const int buf = t & 1;

        if (t + 1 < NT)
            stage4(cbt, t + 1, ldsbuf[buf ^ 1], w, lane);

        const char* bh = &ldsbuf[buf][0];
        const char* bl = &ldsbuf[buf][8192];

        const int cb0 = t * 16 + sl * 4;
        float4 cs = *(const float4*)&c2f[cb0];
        f32x4 a0 = { cs.x, cs.y, cs.z, cs.w };
        f32x4 a1 = { 0.f, 0.f, 0.f, 0.f };
        f32x4 a2 = { 0.f, 0.f, 0.f, 0.f };

        #pragma unroll
        for (int kc = 0; kc < 8; ++kc) {
            const int byt = lanebase + kc * 1024;       // wave reads 1KB contiguous
            bf16x8 ch = *(const bf16x8*)(bh + byt);
            bf16x8 cl = *(const bf16x8*)(bl + byt);
            a0 = __builtin_amdgcn_mfma_f32_16x16x32_bf16(ch, xh[kc], a0, 0, 0, 0);
            a1 = __builtin_amdgcn_mfma_f32_16x16x32_bf16(ch, xl[kc], a1, 0, 0, 0);
            a2 = __builtin_amdgcn_mfma_f32_16x16x32_bf16(cl, xh[kc], a2, 0, 0, 0);
        }

        #pragma unroll
        for (int j = 0; j < 4; ++j) {
            const int code = cb0 + j;
            float m = (a0[j] + a1[j]) + a2[j];
            if (m < tb1)      { tb2 = tb1; ti2 = ti1; tb1 = m; ti1 = code; }
            else if (m < tb2) { tb2 = m; ti2 = code; }
        }

        __syncthreads();
    }

    #pragma unroll
    for (int off = 16; off <= 32; off <<= 1) {
        float ob1 = __shfl_xor(tb1, off, 64);
        int   oi1 = __shfl_xor(ti1, off, 64);
        float ob2 = __shfl_xor(tb2, off, 64);
        int   oi2 = __shfl_xor(ti2, off, 64);
        float nb1, ca, cs2; int ni1, cai, csi;
        bool oless = (ob1 < tb1) || (ob1 == tb1 && oi1 < ti1);
        if (oless) { nb1 = ob1; ni1 = oi1; ca = tb1; cai = ti1; cs2 = ob2; csi = oi2; }
        else       { nb1 = tb1; ni1 = ti1; ca = ob1; cai = oi1; cs2 = tb2; csi = ti2; }
        if (cs2 < ca || (cs2 == ca && csi < cai)) { tb2 = cs2; ti2 = csi; }
        else                                      { tb2 = ca;  ti2 = cai; }
        tb1 = nb1; ti1 = ni1;
    }

    if (lane < 16) {
        const int lp = w * 16 + lane;
        if (tb2 - tb1 < EPS_FLAG) {
            int pos = atomicAdd(cnt, 1);
            list[pos] = n0 + lp;
        }
    }

    #pragma unroll 4
    for (int p = 0; p < 16; ++p) {
        const int row = __shfl(ti1, p, 64);
        const float4* srcr = (const float4*)(cb + (size_t)row * DIMS);
        float4*       dstr = (float4*)(out + (size_t)(n0 + w * 16 + p) * DIMS);
        dstr[lane] = srcr[lane];
    }
}

// ---------- kernel C: exact fp64 re-check, ILP-unrolled coalesced scan ------
__global__ __launch_bounds__(256) void vq_refine_kernel(const float* __restrict__ x,
                                                        const float* __restrict__ cb,
                                                        const int* __restrict__ cnt,
                                                        const int* __restrict__ list,
                                                        float* __restrict__ out) {
    __shared__ double wd1[4], wd2[4];
    __shared__ int    wi1[4], wi2[4];
    __shared__ int    sel;

    const int tid  = threadIdx.x;
    const int lane = tid & 63;
    const int w    = tid >> 6;
    const int count = cnt[0];

    for (int li = blockIdx.x; li < count; li += gridDim.x) {
        const int n = list[li];

        float4 xv = ((const float4*)(x + (size_t)n * DIMS))[lane];
        const double x0 = (double)xv.x, x1 = (double)xv.y;
        const double x2 = (double)xv.z, x3 = (double)xv.w;

        double b1 = 1.0e300, b2 = 1.0e300;
        int    i1 = 0,       i2 = 0;

        const int kw = w * 256;
        for (int kb = 0; kb < 256; kb += 8) {
            double s[8];
            #pragma unroll
            for (int u = 0; u < 8; ++u) {
                float4 cv = ((const float4*)(cb + (size_t)(kw + kb + u) * DIMS))[lane];
                double t0 = x0 - (double)cv.x;
                double t1 = x1 - (double)cv.y;
                double t2 = x2 - (double)cv.z;
                double t3 = x3 - (double)cv.w;
                s[u] = fma(t0, t0, fma(t1, t1, fma(t2, t2, t3 * t3)));
            }
            #pragma unroll
            for (int off = 32; off > 0; off >>= 1) {
                #pragma unroll
                for (int u = 0; u < 8; ++u)
                    s[u] += __shfl_xor(s[u], off, 64);
            }
            #pragma unroll
            for (int u = 0; u < 8; ++u) {
                const int k = kw + kb + u;
                if (s[u] < b1)      { b2 = b1; i2 = i1; b1 = s[u]; i1 = k; }
                else if (s[u] < b2) { b2 = s[u]; i2 = k; }
            }
        }

        if (lane == 0) { wd1[w] = b1; wi1[w] = i1; wd2[w] = b2; wi2[w] = i2; }
        __syncthreads();

        if (tid == 0) {
            double B1 = 1.0e300, B2 = 1.0e300;
            int    J1 = 0,       J2 = 0;
            #pragma unroll
            for (int g = 0; g < 4; ++g) {
                double v = wd1[g]; int ii = wi1[g];
                if (v < B1 || (v == B1 && ii < J1)) { B2 = B1; J2 = J1; B1 = v; J1 = ii; }
                else if (v < B2 || (v == B2 && ii < J2)) { B2 = v; J2 = ii; }
                v = wd2[g]; ii = wi2[g];
                if (v < B1 || (v == B1 && ii < J1)) { B2 = B1; J2 = J1; B1 = v; J1 = ii; }
                else if (v < B2 || (v == B2 && ii < J2)) { B2 = v; J2 = ii; }
            }
            sel = (B2 - B1 < TIE_TOL && J2 < J1) ? J2 : J1;
        }
        __syncthreads();

        const float4* cb4 = (const float4*)(cb + (size_t)sel * DIMS);
        float4*       o4  = (float4*)(out + (size_t)n * DIMS);
        if (tid < 64) o4[tid] = cb4[tid];
        __syncthreads();
    }
}

extern "C" void kernel_launch(void* const* d_in, const int* in_sizes, int n_in,
                              void* d_out, int out_size, void* d_ws, size_t ws_size,
                              hipStream_t stream) {
    const float* x  = (const float*)d_in[0];   // [16,4096,256]
    const float* cb = (const float*)d_in[1];   // [1024,256]
    float* out = (float*)d_out;                // [16,4096,256]

    float* c2f = (float*)d_ws;                           // 1024 floats
    int*   cnt = (int*)((char*)d_ws + 4096);             // 1 int
    int*   lst = (int*)((char*)d_ws + 4112);             // worklist
    char*  cbt = (char*)d_ws + CBT_OFF;                  // 1 MiB bf16 tiles

    vq_prep_kernel<<<128, 256, 0, stream>>>(cb, c2f, cbt, cnt);
    vq_assign_kernel<<<NPTS / BMBLK, 256, 0, stream>>>(x, cb, cbt, c2f, out, cnt, lst);
    vq_refine_kernel<<<256, 256, 0, stream>>>(x, cb, cnt, lst, out);
}